// Round 18
// baseline (3132.118 us; speedup 1.0000x reference)
//
#include <hip/hip_runtime.h>
#include <math.h>

#define VOCAB 32000
#define EMB   256
#define HID   512
#define NB    32
#define TT    128
#define TM1   127
#define SS    128
#define NROWS (TM1*NB)     // 4064
#define NT128 250          // 32000/128

// ---- workspace layout (float32 offsets) ----
#define OFF_ENCW 0          // bf16 [4096][512]  enc@attnW_enc^T + attnb
#define OFF_W0S  1048576    // i8 granules Whh0 [4][32][512] x uint4 = 1 MB
#define OFF_W1S  1310720    // i8 granules Whh1
#define OFF_H0I  1572864    // f32 [32][512] initial states
#define OFF_C0I  1589248
#define OFF_H1I  1605632
#define OFF_C1I  1622016
#define OFF_GX   2686976    // bf16 [4096][2048] g0x rows -> overwritten in-place by g1x
#define OFF_PART OFF_GX     // float2 [4096][250] (after pipe)
#define OFF_ENCB OFF_GX     // bf16 enc staged (pre-g0x only)
#define OFF_CATB 6881280    // bf16 [4096][1024]; emb_bf16 overlays start (pre-g0x)
#define OFF_EMBB OFF_CATB   // bf16 [4096][256]
#define OFF_NLL  8978432
#define OFF_CNT  8982528
#define OFF_CMB0 8986624    // f32 [2048] row scales Whh0
#define OFF_CMB1 8988672    // f32 [2048] Whh1
#define OFF_WX1  8990720    // i8 granules Wih1 = 1 MB (262144 f32)
#define OFF_CMBX 9252864    // f32 [2048] Wih1 scales
#define OFF_H08  9254912    // i8 [4064][512] h0 history = 524288 f32
#define OFF_FLG  9779200    // ints: flag0/flag1/flag2 [32*32] each = 3072
#define OFF_WQ8  9782272    // i8 granules attnWq [32][512] x uint4 = 256 KB (65536 f32)
#define OFF_CMQ  9847808    // f32 [512] attnWq scales
#define OFF_H18  9848320    // i8 [4064][512] h1 history = 524288 f32
// end 10,372,608 f32 = 41.5 MB (ws proven >= 41.85 MB in round 0)

typedef __attribute__((ext_vector_type(8))) short short8;
typedef __attribute__((ext_vector_type(4))) float f32x4;
typedef unsigned long long ull_t;

__device__ __forceinline__ float sigm(float x){ return 1.f/(1.f + __expf(-x)); }
__device__ __forceinline__ float tanh_f(float x){
    x = fminf(fmaxf(x, -15.f), 15.f);
    float e = __expf(2.f*x);
    return (e-1.f)/(e+1.f);
}
__device__ __forceinline__ unsigned short f2b(float f){
    union{float f; unsigned u;} x{f};
    unsigned r = (x.u + 0x7fff + ((x.u>>16)&1)) >> 16;
    return (unsigned short)r;
}
__device__ __forceinline__ float b2f(unsigned short b){
    union{unsigned u; float f;} x{(unsigned)b<<16};
    return x.f;
}
__device__ __forceinline__ ull_t cohl(const ull_t* p){
    return __hip_atomic_load((ull_t*)p, __ATOMIC_RELAXED, __HIP_MEMORY_SCOPE_AGENT);
}
__device__ __forceinline__ void cohs(ull_t* p, ull_t v){
    __hip_atomic_store(p, v, __ATOMIC_RELAXED, __HIP_MEMORY_SCOPE_AGENT);
}
__device__ __forceinline__ int cohli(const int* p){
    return __hip_atomic_load((int*)p, __ATOMIC_RELAXED, __HIP_MEMORY_SCOPE_AGENT);
}
__device__ __forceinline__ void cohsi(int* p, int v){
    __hip_atomic_store(p, v, __ATOMIC_RELAXED, __HIP_MEMORY_SCOPE_AGENT);
}
__device__ __forceinline__ unsigned short cohls(const unsigned short* p){
    return __hip_atomic_load((unsigned short*)p, __ATOMIC_RELAXED, __HIP_MEMORY_SCOPE_AGENT);
}
__device__ __forceinline__ void cohss(unsigned short* p, unsigned short v){
    __hip_atomic_store(p, v, __ATOMIC_RELAXED, __HIP_MEMORY_SCOPE_AGENT);
}

// ------------------------------------------------------------------ init
__global__ void k_init(const float* __restrict__ hid, const float* __restrict__ cel,
                       float* __restrict__ ws){
    int idx = blockIdx.x*256 + threadIdx.x;
    if (idx < 32768){
        int l = idx >> 14, r = idx & 16383;
        int b = r >> 9, k = r & 511;
        float hv = 0.5f*(hid[(2*l)*16384 + b*512 + k] + hid[(2*l+1)*16384 + b*512 + k]);
        float cv = 0.5f*(cel[(2*l)*16384 + b*512 + k] + cel[(2*l+1)*16384 + b*512 + k]);
        ws[(l ? OFF_H1I : OFF_H0I) + b*512 + k] = hv;
        ws[(l ? OFF_C1I : OFF_C0I) + b*512 + k] = cv;
    } else if (idx < 65536){
        int j = idx - 32768;                       // catb pad rows 4064..4095
        ((unsigned short*)(ws + OFF_CATB))[(size_t)4064*1024 + j] = 0;
    } else if (idx < 68608){
        ((int*)(ws + OFF_FLG))[idx - 65536] = 0;   // flags (3072)
    }
}

// ------------------------------------------------- quantize Whh0/Whh1/Wih1/attnWq -> int8
__global__ void __launch_bounds__(256)
k_qpack(const float* __restrict__ Whh0, const float* __restrict__ Whh1,
        const float* __restrict__ Wih1, const float* __restrict__ attnW,
        float* __restrict__ ws){
    __shared__ float red[256];
    __shared__ char qb[512];
    const int r = blockIdx.x;            // 0..6655
    const int layer = r >> 11, row = r & 2047;   // layer 3: row 0..511
    const int g = row >> 9, u = row & 511;
    const float* src;
    if (layer == 0)      src = Whh0 + (size_t)row*512;
    else if (layer == 1) src = Whh1 + (size_t)row*512;
    else if (layer == 2) src = Wih1 + (size_t)row*512;
    else                 src = attnW + (size_t)row*1024;   // query half, K=512
    const int tid = threadIdx.x;
    float w0 = src[tid], w1 = src[tid+256];
    red[tid] = fmaxf(fabsf(w0), fabsf(w1));
    __syncthreads();
    for (int off = 128; off >= 1; off >>= 1){
        if (tid < off) red[tid] = fmaxf(red[tid], red[tid+off]);
        __syncthreads();
    }
    float mx = fmaxf(red[0], 1e-30f);
    float qs = 127.f / mx;
    qb[tid]     = (char)__float2int_rn(w0*qs);
    qb[tid+256] = (char)__float2int_rn(w1*qs);
    __syncthreads();
    const int woff = (layer == 0) ? OFF_W0S : (layer == 1 ? OFF_W1S :
                     (layer == 2 ? OFF_WX1 : OFF_WQ8));
    const int soff = (layer == 0) ? OFF_CMB0 : (layer == 1 ? OFF_CMB1 :
                     (layer == 2 ? OFF_CMBX : OFF_CMQ));
    if (tid < 128){
        int k = tid*4;
        unsigned d =  (unsigned)(unsigned char)qb[k]
                   | ((unsigned)(unsigned char)qb[k+1] << 8)
                   | ((unsigned)(unsigned char)qb[k+2] << 16)
                   | ((unsigned)(unsigned char)qb[k+3] << 24);
        ((unsigned*)(ws + woff))[(((g*32 + (k>>4))*512) + u)*4 + ((k>>2)&3)] = d;
    }
    if (tid == 0) ws[soff + row] = mx / (127.f*127.f);
}

// ------------------------------------------------- stage enc + emb gather to bf16
__global__ void k_cvt(const int* __restrict__ X, const float* __restrict__ emb,
                      const float* __restrict__ enc, float* __restrict__ ws){
    int tix = blockIdx.x*256 + threadIdx.x;
    if (tix < 524288){
        int j = tix*4;                              // enc: 4096x512
        unsigned short* eb = (unsigned short*)(ws + OFF_ENCB);
        #pragma unroll
        for (int e = 0; e < 4; ++e) eb[j+e] = f2b(enc[j+e]);
    } else if (tix < 784480){
        int j = (tix - 524288)*4;                   // emb gather: 4064x256
        if (j < NROWS*EMB){
            int m = j >> 8, k = j & 255;
            int b = m / 127, t = m % 127;
            const float* src = emb + (size_t)X[b*TT + t]*EMB + k;
            unsigned short* mb = (unsigned short*)(ws + OFF_EMBB);
            #pragma unroll
            for (int e = 0; e < 4; ++e) mb[(size_t)m*256 + k + e] = f2b(src[e]);
        }
    }
}

// ------------------------------------------------------------------ 4-stage pipelined scan
// 128 blocks: 0-31 lstm0, 32-63 g1x, 64-95 lstm1, 96-127 attention.
// Forward-only per-batch flag following; i8 weights streamed from L2 per step.
#define DOTLOOP(WP, HQARR, A0, A1, A2, A3) \
    _Pragma("unroll 4") \
    for (int kc2 = 0; kc2 < 32; ++kc2){ \
        uint4 hq = *(const uint4*)&HQARR[kc2*16]; \
        uint4 w0 = WP[(0*32 + kc2)*512]; \
        uint4 w1 = WP[(1*32 + kc2)*512]; \
        uint4 w2 = WP[(2*32 + kc2)*512]; \
        uint4 w3 = WP[(3*32 + kc2)*512]; \
        A0 = __builtin_amdgcn_sdot4((int)w0.x, (int)hq.x, A0, false); \
        A0 = __builtin_amdgcn_sdot4((int)w0.y, (int)hq.y, A0, false); \
        A0 = __builtin_amdgcn_sdot4((int)w0.z, (int)hq.z, A0, false); \
        A0 = __builtin_amdgcn_sdot4((int)w0.w, (int)hq.w, A0, false); \
        A1 = __builtin_amdgcn_sdot4((int)w1.x, (int)hq.x, A1, false); \
        A1 = __builtin_amdgcn_sdot4((int)w1.y, (int)hq.y, A1, false); \
        A1 = __builtin_amdgcn_sdot4((int)w1.z, (int)hq.z, A1, false); \
        A1 = __builtin_amdgcn_sdot4((int)w1.w, (int)hq.w, A1, false); \
        A2 = __builtin_amdgcn_sdot4((int)w2.x, (int)hq.x, A2, false); \
        A2 = __builtin_amdgcn_sdot4((int)w2.y, (int)hq.y, A2, false); \
        A2 = __builtin_amdgcn_sdot4((int)w2.z, (int)hq.z, A2, false); \
        A2 = __builtin_amdgcn_sdot4((int)w2.w, (int)hq.w, A2, false); \
        A3 = __builtin_amdgcn_sdot4((int)w3.x, (int)hq.x, A3, false); \
        A3 = __builtin_amdgcn_sdot4((int)w3.y, (int)hq.y, A3, false); \
        A3 = __builtin_amdgcn_sdot4((int)w3.z, (int)hq.z, A3, false); \
        A3 = __builtin_amdgcn_sdot4((int)w3.w, (int)hq.w, A3, false); \
    }

__global__ void __launch_bounds__(512, 1)
k_pipe(const float* __restrict__ bih1, const float* __restrict__ bhh1,
       const float* __restrict__ enc, const float* __restrict__ v,
       float* __restrict__ ws)
{
    __shared__ __align__(16) char hh8[512];
    __shared__ float wred[8];
    __shared__ float hfacs;
    const int blk = blockIdx.x, u = threadIdx.x;
    const int role = blk >> 5, b = blk & 31;
    char* h0i8 = (char*)(ws + OFF_H08);
    char* h1i8 = (char*)(ws + OFF_H18);
    unsigned short* gx = (unsigned short*)(ws + OFF_GX);
    unsigned short* catb = (unsigned short*)(ws + OFF_CATB);
    int* flag0 = (int*)(ws + OFF_FLG);         // [32] stride 32
    int* flag1 = flag0 + 1024;
    int* flag2 = flag0 + 2048;

    if (role == 0){
        // ================= lstm0: produce h0[t], publish i8 =================
        const uint4* wp = ((const uint4*)(ws + OFF_W0S)) + u;
        const float* comb = ws + OFF_CMB0;
        const float cb0 = comb[u], cb1 = comb[512+u], cb2 = comb[1024+u], cb3 = comb[1536+u];
        float c = ws[OFF_C0I + b*512 + u];
        float h0v = ws[OFF_H0I + b*512 + u];
        {
            float a = fabsf(h0v);
            #pragma unroll
            for (int msk = 32; msk >= 1; msk >>= 1) a = fmaxf(a, __shfl_xor(a, msk));
            if ((u & 63) == 0) wred[u >> 6] = a;
            __syncthreads();
            if (u == 0){
                float m = wred[0];
                #pragma unroll
                for (int i2 = 1; i2 < 8; ++i2) m = fmaxf(m, wred[i2]);
                hfacs = fmaxf(m, 1.f);
            }
            __syncthreads();
        }
        float hmaxc = hfacs;
        hh8[u] = (char)__float2int_rn(h0v * (127.f/hmaxc));
        __syncthreads();
        for (int t = 0; t < TM1; ++t){
            const unsigned short* grow = gx + ((size_t)(b*127 + t))*2048 + u;
            float gxi = b2f(grow[0]),    gxf = b2f(grow[512]);
            float gxg = b2f(grow[1024]), gxo = b2f(grow[1536]);
            int a0 = 0, a1 = 0, a2 = 0, a3 = 0;
            DOTLOOP(wp, hh8, a0, a1, a2, a3)
            float gi = fmaf((float)a0, cb0*hmaxc, gxi);
            float gf = fmaf((float)a1, cb1*hmaxc, gxf);
            float gg = fmaf((float)a2, cb2*hmaxc, gxg);
            float go = fmaf((float)a3, cb3*hmaxc, gxo);
            float cn = sigm(gf)*c + sigm(gi)*tanh_f(gg);
            float hn = sigm(go)*tanh_f(cn);
            c = cn;
            __syncthreads();
            hmaxc = 1.f;
            hh8[u] = (char)__float2int_rn(hn * 127.f);
            __syncthreads();
            if (u < 64)
                cohs((ull_t*)(h0i8 + ((size_t)(b*127 + t))*512) + u, ((ull_t*)hh8)[u]);
            __syncthreads();            // drain wave0 stores before flag
            if (u == 0) cohsi(flag0 + b*32, t + 1);
        }
    } else if (role == 1){
        // ================= g1x worker: g1[t] = Wih1 @ h0[t] + biases =================
        __shared__ __align__(16) char h8[512];
        const uint4* wp = ((const uint4*)(ws + OFF_WX1)) + u;
        const float* comb = ws + OFF_CMBX;
        const float cb0 = comb[u], cb1 = comb[512+u], cb2 = comb[1024+u], cb3 = comb[1536+u];
        const float gb0 = bih1[u]        + bhh1[u];
        const float gb1 = bih1[512+u]    + bhh1[512+u];
        const float gb2 = bih1[1024+u]   + bhh1[1024+u];
        const float gb3 = bih1[1536+u]   + bhh1[1536+u];
        for (int t = 0; t < TM1; ++t){
            if (u == 0){
                while (cohli(flag0 + b*32) < t + 1) __builtin_amdgcn_s_sleep(2);
            }
            __syncthreads();
            if (u < 64)
                ((ull_t*)h8)[u] = cohl((const ull_t*)(h0i8 + ((size_t)(b*127 + t))*512) + u);
            __syncthreads();
            int a0 = 0, a1 = 0, a2 = 0, a3 = 0;
            DOTLOOP(wp, h8, a0, a1, a2, a3)
            unsigned short* gr = gx + ((size_t)(b*127 + t))*2048;
            cohss(gr + u,      f2b(fmaf((float)a0, cb0, gb0)));
            cohss(gr + 512+u,  f2b(fmaf((float)a1, cb1, gb1)));
            cohss(gr + 1024+u, f2b(fmaf((float)a2, cb2, gb2)));
            cohss(gr + 1536+u, f2b(fmaf((float)a3, cb3, gb3)));
            __syncthreads();            // all waves' gate stores drained
            if (u == 0) cohsi(flag1 + b*32, t + 1);
        }
    } else if (role == 2){
        // ================= lstm1: consume g1[t], own Whh1 recurrence =================
        const uint4* wp = ((const uint4*)(ws + OFF_W1S)) + u;
        const float* comb = ws + OFF_CMB1;
        const float cb0 = comb[u], cb1 = comb[512+u], cb2 = comb[1024+u], cb3 = comb[1536+u];
        float c = ws[OFF_C1I + b*512 + u];
        float h1v = ws[OFF_H1I + b*512 + u];
        {
            float a = fabsf(h1v);
            #pragma unroll
            for (int msk = 32; msk >= 1; msk >>= 1) a = fmaxf(a, __shfl_xor(a, msk));
            if ((u & 63) == 0) wred[u >> 6] = a;
            __syncthreads();
            if (u == 0){
                float m = wred[0];
                #pragma unroll
                for (int i2 = 1; i2 < 8; ++i2) m = fmaxf(m, wred[i2]);
                hfacs = fmaxf(m, 1.f);
            }
            __syncthreads();
        }
        float hmaxc = hfacs;
        hh8[u] = (char)__float2int_rn(h1v * (127.f/hmaxc));
        __syncthreads();
        for (int t = 0; t < TM1; ++t){
            if (u == 0){
                while (cohli(flag1 + b*32) < t + 1) __builtin_amdgcn_s_sleep(2);
            }
            __syncthreads();
            const unsigned short* gr = gx + ((size_t)(b*127 + t))*2048;
            float gxi = b2f(cohls(gr + u));
            float gxf = b2f(cohls(gr + 512+u));
            float gxg = b2f(cohls(gr + 1024+u));
            float gxo = b2f(cohls(gr + 1536+u));
            int a0 = 0, a1 = 0, a2 = 0, a3 = 0;
            DOTLOOP(wp, hh8, a0, a1, a2, a3)
            float gi = fmaf((float)a0, cb0*hmaxc, gxi);
            float gf = fmaf((float)a1, cb1*hmaxc, gxf);
            float gg = fmaf((float)a2, cb2*hmaxc, gxg);
            float go = fmaf((float)a3, cb3*hmaxc, gxo);
            float cn = sigm(gf)*c + sigm(gi)*tanh_f(gg);
            float hn = sigm(go)*tanh_f(cn);
            c = cn;
            __syncthreads();
            hmaxc = 1.f;
            hh8[u] = (char)__float2int_rn(hn * 127.f);
            catb[((size_t)(t*32 + b))*1024 + u] = f2b(hn);
            __syncthreads();
            if (u < 64)
                cohs((ull_t*)(h1i8 + ((size_t)(b*127 + t))*512) + u, ((ull_t*)hh8)[u]);
            __syncthreads();            // drain wave0 stores before flag
            if (u == 0) cohsi(flag2 + b*32, t + 1);
        }
    } else {
        // ================= attention worker: hq -> scores -> softmax -> weighted =================
        __shared__ __align__(16) char h1q[512];
        __shared__ float hqf[512], vvv[512], attv[128], rbuf[2];
        const uint4* wq = (const uint4*)(ws + OFF_WQ8);
        const float scq = ws[OFF_CMQ + u];
        const unsigned short* encwb = (const unsigned short*)(ws + OFF_ENCW);
        vvv[u] = v[u];
        __syncthreads();
        for (int t = 0; t < TM1; ++t){
            if (u == 0){
                while (cohli(flag2 + b*32) < t + 1) __builtin_amdgcn_s_sleep(2);
            }
            __syncthreads();
            if (u < 64)
                ((ull_t*)h1q)[u] = cohl((const ull_t*)(h1i8 + ((size_t)(b*127 + t))*512) + u);
            __syncthreads();
            {   // hq[u] = attnWq row u . h1  (i8 x i8)
                int a = 0;
                #pragma unroll 4
                for (int kc2 = 0; kc2 < 32; ++kc2){
                    uint4 hv = *(const uint4*)&h1q[kc2*16];
                    uint4 w = wq[kc2*512 + u];
                    a = __builtin_amdgcn_sdot4((int)w.x, (int)hv.x, a, false);
                    a = __builtin_amdgcn_sdot4((int)w.y, (int)hv.y, a, false);
                    a = __builtin_amdgcn_sdot4((int)w.z, (int)hv.z, a, false);
                    a = __builtin_amdgcn_sdot4((int)w.w, (int)hv.w, a, false);
                }
                hqf[u] = (float)a * scq;
            }
            __syncthreads();
            {   // scores: 4 threads per s
                int s = u >> 2, q = u & 3;
                const unsigned short* eb = encwb + ((size_t)(b*SS + s))*512 + q*128;
                const float* hp = hqf + q*128;
                const float* vp = vvv + q*128;
                float p0 = 0.f, p1 = 0.f;
                #pragma unroll 2
                for (int k = 0; k < 128; k += 2){
                    p0 += tanh_f(hp[k]   + b2f(eb[k]))   * vp[k];
                    p1 += tanh_f(hp[k+1] + b2f(eb[k+1])) * vp[k+1];
                }
                float p = p0 + p1;
                p += __shfl_xor(p, 1);
                p += __shfl_xor(p, 2);
                if (q == 0) attv[s] = p;
            }
            __syncthreads();
            float e0 = 0.f, e1 = 0.f;
            if (u < 64){
                float m2 = fmaxf(attv[u], attv[u+64]);
                #pragma unroll
                for (int msk = 32; msk >= 1; msk >>= 1) m2 = fmaxf(m2, __shfl_xor(m2, msk));
                if (u == 0) rbuf[0] = m2;
            }
            __syncthreads();
            float M = rbuf[0];
            if (u < 64){
                e0 = __expf(attv[u] - M);
                e1 = __expf(attv[u+64] - M);
                float sum = e0 + e1;
                #pragma unroll
                for (int msk = 32; msk >= 1; msk >>= 1) sum += __shfl_xor(sum, msk);
                if (u == 0) rbuf[1] = sum;
            }
            __syncthreads();
            if (u < 64){
                float inv = 1.f / rbuf[1];
                attv[u] = e0*inv; attv[u+64] = e1*inv;
            }
            __syncthreads();
            {   // weighted[u] = sum_s att[s] * enc[b,s,u]
                const float* eb2 = enc + ((size_t)(b*SS))*512 + u;
                float w0 = 0.f, w1 = 0.f;
                #pragma unroll 4
                for (int s = 0; s < 128; s += 2){
                    w0 += attv[s]   * eb2[(s  )*512];
                    w1 += attv[s+1] * eb2[(s+1)*512];
                }
                catb[((size_t)(t*32 + b))*1024 + 512 + u] = f2b(w0 + w1);
            }
            __syncthreads();
        }
    }
}

// ------------------------------------------------------------------ generic MFMA GEMM
__global__ void __launch_bounds__(256)
k_gemm(const unsigned short* __restrict__ A, int lda,
       const float* __restrict__ B, int ldb,
       const float* __restrict__ bias1, const float* __restrict__ bias2,
       unsigned short* __restrict__ C, int ldc, int nkk)
{
    __shared__ unsigned short As[128*32];
    __shared__ unsigned short Bs[128*32];
    const int tid = threadIdx.x;
    const int mt = blockIdx.x, nt = blockIdx.y;
    const int m0 = mt*128, n0 = nt*128;
    const int lane = tid & 63, wid = tid >> 6;
    const int wr = wid >> 1, wc = wid & 1;
    const int lr = lane & 15, lg = lane >> 4;
    const int ar = tid & 127, ah = tid >> 7;
    const int br = tid >> 1,  bh = tid & 1;
    f32x4 acc[4][4];
    #pragma unroll
    for (int i=0;i<4;i++)
        #pragma unroll
        for (int j=0;j<4;j++) acc[i][j] = (f32x4){0.f,0.f,0.f,0.f};

    for (int kk = 0; kk < nkk; ++kk){
        const int k0 = kk*32;
        uint4 a0 = *(const uint4*)(A + (size_t)(m0+ar)*lda + k0 + ah*16);
        uint4 a1 = *(const uint4*)(A + (size_t)(m0+ar)*lda + k0 + ah*16 + 8);
        const float* bsrc = B + (size_t)(n0+br)*ldb + k0 + bh*16;
        float4 f0 = *(const float4*)(bsrc);
        float4 f1 = *(const float4*)(bsrc+4);
        float4 f2 = *(const float4*)(bsrc+8);
        float4 f3 = *(const float4*)(bsrc+12);
        __syncthreads();
        {
            int swz = (ar>>1)&3;
            *(uint4*)&As[ar*32 + ((2*ah  )^swz)*8] = a0;
            *(uint4*)&As[ar*32 + ((2*ah+1)^swz)*8] = a1;
        }
        {
            uint4 p0, p1;
            p0.x = __builtin_amdgcn_perm(__float_as_uint(f0.y), __float_as_uint(f0.x), 0x07060302u);
            p0.y = __builtin_amdgcn_perm(__float_as_uint(f0.w), __float_as_uint(f0.z), 0x07060302u);
            p0.z = __builtin_amdgcn_perm(__float_as_uint(f1.y), __float_as_uint(f1.x), 0x07060302u);
            p0.w = __builtin_amdgcn_perm(__float_as_uint(f1.w), __float_as_uint(f1.z), 0x07060302u);
            p1.x = __builtin_amdgcn_perm(__float_as_uint(f2.y), __float_as_uint(f2.x), 0x07060302u);
            p1.y = __builtin_amdgcn_perm(__float_as_uint(f2.w), __float_as_uint(f2.z), 0x07060302u);
            p1.z = __builtin_amdgcn_perm(__float_as_uint(f3.y), __float_as_uint(f3.x), 0x07060302u);
            p1.w = __builtin_amdgcn_perm(__float_as_uint(f3.w), __float_as_uint(f3.z), 0x07060302u);
            int swz = (br>>1)&3;
            *(uint4*)&Bs[br*32 + ((2*bh  )^swz)*8] = p0;
            *(uint4*)&Bs[br*32 + ((2*bh+1)^swz)*8] = p1;
        }
        __syncthreads();
        short8 av[4], bv[4];
        #pragma unroll
        for (int mi=0; mi<4; ++mi){
            int r = wr*64 + mi*16 + lr;
            av[mi] = *(const short8*)&As[r*32 + ((lg ^ ((r>>1)&3))*8)];
        }
        #pragma unroll
        for (int ni=0; ni<4; ++ni){
            int r = wc*64 + ni*16 + lr;
            bv[ni] = *(const short8*)&Bs[r*32 + ((lg ^ ((r>>1)&3))*8)];
        }
        #pragma unroll
        for (int mi=0; mi<4; ++mi)
            #pragma unroll
            for (int ni=0; ni<4; ++ni)
                acc[mi][ni] = __builtin_amdgcn_mfma_f32_16x16x32_bf16(av[mi], bv[ni], acc[mi][ni], 0, 0, 0);
    }
    int coln[4]; float bsv[4];
    #pragma unroll
    for (int ni=0; ni<4; ++ni){
        coln[ni] = n0 + wc*64 + ni*16 + lr;
        float bv2 = 0.f;
        if (bias1) bv2 += bias1[coln[ni]];
        if (bias2) bv2 += bias2[coln[ni]];
        bsv[ni] = bv2;
    }
    #pragma unroll
    for (int mi=0; mi<4; ++mi)
        #pragma unroll
        for (int ni=0; ni<4; ++ni)
            #pragma unroll
            for (int reg=0; reg<4; ++reg){
                int row = m0 + wr*64 + mi*16 + lg*4 + reg;
                C[(size_t)row*ldc + coln[ni]] = f2b(acc[mi][ni][reg] + bsv[ni]);
            }
}

// ------------------------------------------------------------------ fc MFMA GEMM + LSE partials
__global__ void __launch_bounds__(256)
k_fc(const float* __restrict__ fcW, const float* __restrict__ fcb, float* __restrict__ ws){
    __shared__ unsigned short As[128*32];
    __shared__ unsigned short Bs[128*32];
    __shared__ float eM[128], eS[128];
    const int tid = threadIdx.x;
    const int bid = blockIdx.x;
    const int g = (bid & 7)*1000 + (bid >> 3);
    const int nt = g / 32, mt = g % 32;
    const int m0 = mt*128, n0 = nt*128;
    const unsigned short* catb = (const unsigned short*)(ws + OFF_CATB);
    const int lane = tid & 63, wid = tid >> 6;
    const int wr = wid >> 1, wc = wid & 1;
    const int lr = lane & 15, lg = lane >> 4;
    const int ar = tid & 127, ah = tid >> 7;
    const int br = tid >> 1,  bh = tid & 1;
    f32x4 acc[4][4];
    #pragma unroll
    for (int i=0;i<4;i++)
        #pragma unroll
        for (int j=0;j<4;j++) acc[i][j] = (f32x4){0.f,0.f,0.f,0.f};

    for (int kk = 0; kk < 32; ++kk){
        const int k0 = kk*32;
        uint4 a0 = *(const uint4*)(catb + (size_t)(m0+ar)*1024 + k0 + ah*16);
        uint4 a1 = *(const uint4*)(catb + (size_t)(m0+ar)*1024 + k0 + ah*16 + 8);
        const float* bsrc = fcW + (size_t)(n0+br)*1024 + k0 + bh*16;
        float4 f0 = *(const float4*)(bsrc);
        float4 f1 = *(const float4*)(bsrc+4);
        float4 f2 = *(const float4*)(bsrc+8);
        float4 f3 = *(const float4*)(bsrc+12);
        __syncthreads();
        {
            int swz = (ar>>1)&3;
            *(uint4*)&As[ar*32 + ((2*ah  )^swz)*8] = a0;
            *(uint4*)&As[ar*32 + ((2*ah+1)^swz)*8] = a1;
        }
        {
            uint4 p0, p1;
            p0.x = __builtin_amdgcn_perm(__float_as_uint(f0.y), __float_as_uint(f0.x), 0x07060302u);
            p0.y = __builtin_amdgcn_perm(__float_as_uint(f0.w), __float_as_uint(f0.z), 0x07060302u);
            p0.z = __builtin_amdgcn_perm(__float_as_uint(f1.y), __float_as_uint(f1.x), 0x07060302u);
            p0.w = __builtin_amdgcn_perm(__float_as_uint(f1.w), __float_as_uint(f1.z), 0x07060302u);
            p1.x = __builtin_amdgcn_perm(__float_as_uint(f2.y), __float_as_uint(f2.x), 0x07060302u);
            p1.y = __builtin_amdgcn_perm(__float_as_uint(f2.w), __float_as_uint(f2.z), 0x07060302u);
            p1.z = __builtin_amdgcn_perm(__float_as_uint(f3.y), __float_as_uint(f3.x), 0x07060302u);
            p1.w = __builtin_amdgcn_perm(__float_as_uint(f3.w), __float_as_uint(f3.z), 0x07060302u);
            int swz = (br>>1)&3;
            *(uint4*)&Bs[br*32 + ((2*bh  )^swz)*8] = p0;
            *(uint4*)&Bs[br*32 + ((2*bh+1)^swz)*8] = p1;
        }
        __syncthreads();
        short8 av[4], bv[4];
        #pragma unroll
        for (int mi=0; mi<4; ++mi){
            int r = wr*64 + mi*16 + lr;
            av[mi] = *(const short8*)&As[r*32 + ((lg ^ ((r>>1)&3))*8)];
        }
        #pragma unroll
        for (int ni=0; ni<4; ++ni){
            int r = wc*64 + ni*16 + lr;
            bv[ni] = *(const short8*)&Bs[r*32 + ((lg ^ ((r>>1)&3))*8)];
        }
        #pragma unroll
        for (int mi=0; mi<4; ++mi)
            #pragma unroll
            for (int ni=0; ni<4; ++ni)
                acc[mi][ni] = __builtin_amdgcn_mfma_f32_16x16x32_bf16(av[mi], bv[ni], acc[mi][ni], 0, 0, 0);
    }
    float bias[4];
    #pragma unroll
    for (int ni=0; ni<4; ++ni) bias[ni] = fcb[n0 + wc*64 + ni*16 + lr];
    float mxA[4][4], smA[4][4];
    #pragma unroll
    for (int mi=0; mi<4; ++mi){
        #pragma unroll
        for (int reg=0; reg<4; ++reg){
            float mx = -3.4e38f;
            #pragma unroll
            for (int ni=0; ni<4; ++ni) mx = fmaxf(mx, acc[mi][ni][reg] + bias[ni]);
            #pragma unroll
            for (int msk=8; msk>=1; msk>>=1) mx = fmaxf(mx, __shfl_xor(mx, msk));
            float sm = 0.f;
            #pragma unroll
            for (int ni=0; ni<4; ++ni) sm += __expf(acc[mi][ni][reg] + bias[ni] - mx);
            #pragma unroll
            for (int msk=8; msk>=1; msk>>=1) sm += __shfl_xor(sm, msk);
            mxA[mi][reg] = mx; smA[mi][reg] = sm;
            if (wc == 0 && lr == 0){
                int rl = wr*64 + mi*16 + lg*4 + reg;
                eM[rl] = mx; eS[rl] = sm;
            }
        }
    }
    __syncthreads();
    if (wc == 1 && lr == 0){
        float2* part = (float2*)(ws + OFF_PART);
        #pragma unroll
        for (int mi=0; mi<4; ++mi){
            #pragma unroll
            for (int reg=0; reg<4; ++reg){
                int rl = wr*64 + mi*16 + lg*4 + reg;
                float m0v = eM[rl], s0 = eS[rl];
                float m1v = mxA[mi][reg], s1 = smA[mi][reg];
                float M = fmaxf(m0v, m1v);
                float S = s0*__expf(m0v - M) + s1*__expf(m1v - M);
                part[(size_t)(m0 + rl)*NT128 + nt] = make_float2(M, S);
            }
        }
    }
}

// ------------------------------------------- per-row LSE combine + target logit
__global__ void k_row(const int* __restrict__ X, const float* __restrict__ fcW,
                      const float* __restrict__ fcb, float* __restrict__ ws){
    __shared__ float LM[256], LS[256];
    int m = blockIdx.x, tid = threadIdx.x;
    const float2* p = (const float2*)(ws + OFF_PART);
    float M = -3.4e38f, Ssum = 0.f;
    if (tid < NT128){
        float2 q = p[(size_t)m*NT128 + tid];
        M = q.x; Ssum = q.y;
    }
    LM[tid] = M; LS[tid] = Ssum;
    __syncthreads();
    for (int off = 128; off >= 1; off >>= 1){
        if (tid < off){
            float m1 = LM[tid], s1 = LS[tid];
            float m2 = LM[tid+off], s2 = LS[tid+off];
            float mm = fmaxf(m1, m2);
            LM[tid] = mm;
            LS[tid] = s1*__expf(m1-mm) + s2*__expf(m2-mm);
        }
        __syncthreads();
    }
    float lse = LM[0] + __logf(LS[0]);
    __syncthreads();
    int t = m >> 5, b = m & 31;
    int y = X[b*TT + t + 1];
    const unsigned short* cr = (const unsigned short*)(ws + OFF_CATB) + (size_t)m*1024;
    const float* wr = fcW + (size_t)y*1024;
    float a = 0.f;
    #pragma unroll
    for (int k = 0; k < 4; ++k) a += b2f(cr[tid*4+k]) * wr[tid*4+k];
    LM[tid] = a;
    __syncthreads();
    for (int off = 128; off >= 1; off >>= 1){
        if (tid < off) LM[tid] += LM[tid+off];
        __syncthreads();
    }
    if (tid == 0){
        float tl = LM[0] + fcb[y];
        float nll = lse - tl;
        int valid = (y != 0);
        ws[OFF_NLL + m] = valid ? nll : 0.f;
        ws[OFF_CNT + m] = valid ? 1.f : 0.f;
    }
}

// ------------------------------------------------------------------ finalize
__global__ void k_fin(const float* __restrict__ ws, float* __restrict__ out){
    __shared__ float red[256];
    int tid = threadIdx.x;
    float lt = 0.f;
    if (tid < TM1){
        float s = 0.f, c = 0.f;
        for (int b=0;b<NB;b++){
            s += ws[OFF_NLL + tid*NB + b];
            c += ws[OFF_CNT + tid*NB + b];
        }
        lt = s / fmaxf(c, 1.f);
    }
    red[tid] = lt;
    __syncthreads();
    for (int off=128; off>=1; off>>=1){
        if (tid < off) red[tid] += red[tid+off];
        __syncthreads();
    }
    if (tid == 0) out[0] = red[0] / (float)TM1;
}

// -------------------------------------------------------------------- launch
extern "C" void kernel_launch(void* const* d_in, const int* in_sizes, int n_in,
                              void* d_out, int out_size, void* d_ws, size_t ws_size,
                              hipStream_t stream) {
    const int*   X     = (const int*)  d_in[0];
    const float* enc   = (const float*)d_in[1];
    const float* hid   = (const float*)d_in[2];
    const float* cel   = (const float*)d_in[3];
    const float* emb   = (const float*)d_in[4];
    const float* Wih0  = (const float*)d_in[5];
    const float* Whh0  = (const float*)d_in[6];
    const float* bih0  = (const float*)d_in[7];
    const float* bhh0  = (const float*)d_in[8];
    const float* Wih1  = (const float*)d_in[9];
    const float* Whh1  = (const float*)d_in[10];
    const float* bih1  = (const float*)d_in[11];
    const float* bhh1  = (const float*)d_in[12];
    const float* attnW = (const float*)d_in[13];
    const float* attnb = (const float*)d_in[14];
    const float* v     = (const float*)d_in[15];
    const float* fcW   = (const float*)d_in[16];
    const float* fcb   = (const float*)d_in[17];
    float* ws  = (float*)d_ws;
    float* out = (float*)d_out;

    unsigned short* encb = (unsigned short*)(ws + OFF_ENCB);
    unsigned short* embb = (unsigned short*)(ws + OFF_EMBB);
    unsigned short* encw = (unsigned short*)(ws + OFF_ENCW);
    unsigned short* g0x  = (unsigned short*)(ws + OFF_GX);

    k_init<<<320, 256, 0, stream>>>(hid, cel, ws);
    k_qpack<<<6656, 256, 0, stream>>>(Whh0, Whh1, Wih1, attnW, ws);
    k_cvt<<<3065, 256, 0, stream>>>(X, emb, enc, ws);
    // encW = enc_bf16 @ attnW[:,512:]^T + attnb
    k_gemm<<<dim3(32,4), 256, 0, stream>>>(encb, 512, attnW + 512, 1024,
                                           attnb, (const float*)nullptr,
                                           encw, 512, 16);
    // g0x = emb_bf16 @ Wih0^T + biases
    k_gemm<<<dim3(32,16), 256, 0, stream>>>(embb, 256, Wih0, 256, bih0, bhh0,
                                            g0x, 2048, 8);
    // 4-stage pipelined scan (lstm0 || g1x || lstm1 || attention)
    {
        void* args[] = {(void*)&bih1, (void*)&bhh1, (void*)&enc, (void*)&v, (void*)&ws};
        (void)hipLaunchCooperativeKernel((const void*)k_pipe, dim3(128), dim3(512),
                                         args, 0, stream);
    }
    k_fc<<<8000, 256, 0, stream>>>(fcW, fcb, ws);
    k_row<<<NROWS, 256, 0, stream>>>(X, fcW, fcb, ws);
    k_fin<<<1, 256, 0, stream>>>(ws, out);
}

// Round 19
// 2076.652 us; speedup vs baseline: 1.5083x; 1.5083x over previous
//
#include <hip/hip_runtime.h>
#include <math.h>

#define VOCAB 32000
#define EMB   256
#define HID   512
#define NB    32
#define TT    128
#define TM1   127
#define SS    128
#define NROWS (TM1*NB)     // 4064
#define NT128 250          // 32000/128

// ---- workspace layout (float32 offsets) ----
#define OFF_ENCW 0          // bf16 [4096][512]  enc@attnW_enc^T + attnb
#define OFF_W0S  1048576    // i8 granules Whh0 [4][32][512] x uint4 = 1 MB
#define OFF_W1S  1310720    // i8 granules Whh1
#define OFF_H0I  1572864    // f32 [32][512] initial states
#define OFF_C0I  1589248
#define OFF_H1I  1605632
#define OFF_C1I  1622016
#define OFF_H0H  1638400    // (free during pipe) HQ output region [4096][512] bf16
#define OFF_HQ   OFF_H0H
#define OFF_GX   2686976    // bf16 [4096][2048] g0x rows -> overwritten in-place by g1x
#define OFF_PART OFF_GX     // float2 [4096][250] (after pipe)
#define OFF_ENCB OFF_GX     // bf16 enc staged (pre-g0x only)
#define OFF_CATB 6881280    // bf16 [4096][1024]; emb_bf16 overlays start (pre-g0x)
#define OFF_EMBB OFF_CATB   // bf16 [4096][256]
#define OFF_NLL  8978432
#define OFF_CNT  8982528
#define OFF_CMB0 8986624    // f32 [2048] row scales Whh0
#define OFF_CMB1 8988672    // f32 [2048] Whh1
#define OFF_WX1  8990720    // i8 granules Wih1 = 1 MB (262144 f32)
#define OFF_CMBX 9252864    // f32 [2048] Wih1 scales
#define OFF_H08  9254912    // i8 [4064][512] h0 history (pad to 4096) = 524288 f32
#define OFF_FLG  9779200    // ints: flag0[32*32] flag1[32*32] = 2048
// end 9,781,248 f32 = 39.1 MB (ws proven >= 41.9 MB in round 0)

typedef __attribute__((ext_vector_type(8))) short short8;
typedef __attribute__((ext_vector_type(4))) float f32x4;
typedef unsigned long long ull_t;

__device__ __forceinline__ float sigm(float x){ return 1.f/(1.f + __expf(-x)); }
__device__ __forceinline__ float tanh_f(float x){
    x = fminf(fmaxf(x, -15.f), 15.f);
    float e = __expf(2.f*x);
    return (e-1.f)/(e+1.f);
}
__device__ __forceinline__ unsigned short f2b(float f){
    union{float f; unsigned u;} x{f};
    unsigned r = (x.u + 0x7fff + ((x.u>>16)&1)) >> 16;
    return (unsigned short)r;
}
__device__ __forceinline__ float b2f(unsigned short b){
    union{unsigned u; float f;} x{(unsigned)b<<16};
    return x.f;
}
__device__ __forceinline__ ull_t cohl(const ull_t* p){
    return __hip_atomic_load((ull_t*)p, __ATOMIC_RELAXED, __HIP_MEMORY_SCOPE_AGENT);
}
__device__ __forceinline__ void cohs(ull_t* p, ull_t v){
    __hip_atomic_store(p, v, __ATOMIC_RELAXED, __HIP_MEMORY_SCOPE_AGENT);
}
__device__ __forceinline__ int cohli(const int* p){
    return __hip_atomic_load((int*)p, __ATOMIC_RELAXED, __HIP_MEMORY_SCOPE_AGENT);
}
__device__ __forceinline__ void cohsi(int* p, int v){
    __hip_atomic_store(p, v, __ATOMIC_RELAXED, __HIP_MEMORY_SCOPE_AGENT);
}
__device__ __forceinline__ unsigned short cohls(const unsigned short* p){
    return __hip_atomic_load((unsigned short*)p, __ATOMIC_RELAXED, __HIP_MEMORY_SCOPE_AGENT);
}
__device__ __forceinline__ void cohss(unsigned short* p, unsigned short v){
    __hip_atomic_store(p, v, __ATOMIC_RELAXED, __HIP_MEMORY_SCOPE_AGENT);
}

// ------------------------------------------------------------------ init
__global__ void k_init(const float* __restrict__ hid, const float* __restrict__ cel,
                       float* __restrict__ ws){
    int idx = blockIdx.x*256 + threadIdx.x;
    if (idx < 32768){
        int l = idx >> 14, r = idx & 16383;
        int b = r >> 9, k = r & 511;
        float hv = 0.5f*(hid[(2*l)*16384 + b*512 + k] + hid[(2*l+1)*16384 + b*512 + k]);
        float cv = 0.5f*(cel[(2*l)*16384 + b*512 + k] + cel[(2*l+1)*16384 + b*512 + k]);
        ws[(l ? OFF_H1I : OFF_H0I) + b*512 + k] = hv;
        ws[(l ? OFF_C1I : OFF_C0I) + b*512 + k] = cv;
    } else if (idx < 65536){
        int j = idx - 32768;                       // catb pad rows 4064..4095
        ((unsigned short*)(ws + OFF_CATB))[(size_t)4064*1024 + j] = 0;
    } else if (idx < 67584){
        ((int*)(ws + OFF_FLG))[idx - 65536] = 0;   // flags
    }
}

// ------------------------------------------------- quantize Whh0/Whh1/Wih1 -> int8
__global__ void __launch_bounds__(256)
k_qpack(const float* __restrict__ Whh0, const float* __restrict__ Whh1,
        const float* __restrict__ Wih1, float* __restrict__ ws){
    __shared__ float red[256];
    __shared__ char qb[512];
    const int r = blockIdx.x;            // 0..6143
    const int layer = r >> 11, row = r & 2047;
    const int g = row >> 9, u = row & 511;
    const float* W = (layer == 0) ? Whh0 : (layer == 1 ? Whh1 : Wih1);
    const float* src = W + (size_t)row*512;
    const int tid = threadIdx.x;
    float w0 = src[tid], w1 = src[tid+256];
    red[tid] = fmaxf(fabsf(w0), fabsf(w1));
    __syncthreads();
    for (int off = 128; off >= 1; off >>= 1){
        if (tid < off) red[tid] = fmaxf(red[tid], red[tid+off]);
        __syncthreads();
    }
    float mx = fmaxf(red[0], 1e-30f);
    float qs = 127.f / mx;
    qb[tid]     = (char)__float2int_rn(w0*qs);
    qb[tid+256] = (char)__float2int_rn(w1*qs);
    __syncthreads();
    const int woff = (layer == 0) ? OFF_W0S : (layer == 1 ? OFF_W1S : OFF_WX1);
    const int soff = (layer == 0) ? OFF_CMB0 : (layer == 1 ? OFF_CMB1 : OFF_CMBX);
    if (tid < 128){
        int k = tid*4;
        unsigned d =  (unsigned)(unsigned char)qb[k]
                   | ((unsigned)(unsigned char)qb[k+1] << 8)
                   | ((unsigned)(unsigned char)qb[k+2] << 16)
                   | ((unsigned)(unsigned char)qb[k+3] << 24);
        ((unsigned*)(ws + woff))[(((g*32 + (k>>4))*512) + u)*4 + ((k>>2)&3)] = d;
    }
    if (tid == 0) ws[soff + row] = mx / (127.f*127.f);
}

// ------------------------------------------------- stage enc + emb gather to bf16
__global__ void k_cvt(const int* __restrict__ X, const float* __restrict__ emb,
                      const float* __restrict__ enc, float* __restrict__ ws){
    int tix = blockIdx.x*256 + threadIdx.x;
    if (tix < 524288){
        int j = tix*4;                              // enc: 4096x512
        unsigned short* eb = (unsigned short*)(ws + OFF_ENCB);
        #pragma unroll
        for (int e = 0; e < 4; ++e) eb[j+e] = f2b(enc[j+e]);
    } else if (tix < 784480){
        int j = (tix - 524288)*4;                   // emb gather: 4064x256
        if (j < NROWS*EMB){
            int m = j >> 8, k = j & 255;
            int b = m / 127, t = m % 127;
            const float* src = emb + (size_t)X[b*TT + t]*EMB + k;
            unsigned short* mb = (unsigned short*)(ws + OFF_EMBB);
            #pragma unroll
            for (int e = 0; e < 4; ++e) mb[(size_t)m*256 + k + e] = f2b(src[e]);
        }
    }
}

// ------------------------------------------------------------------ 3-stage pipelined scan
// 96 blocks: 0-31 lstm0, 32-63 g1x workers, 64-95 lstm1. Forward-only per-batch
// flag following; each stage streams 1 MB/step i8 weights from L2.
#define DOTLOOP(WP, HQARR, A0, A1, A2, A3) \
    _Pragma("unroll 4") \
    for (int kc2 = 0; kc2 < 32; ++kc2){ \
        uint4 hq = *(const uint4*)&HQARR[kc2*16]; \
        uint4 w0 = WP[(0*32 + kc2)*512]; \
        uint4 w1 = WP[(1*32 + kc2)*512]; \
        uint4 w2 = WP[(2*32 + kc2)*512]; \
        uint4 w3 = WP[(3*32 + kc2)*512]; \
        A0 = __builtin_amdgcn_sdot4((int)w0.x, (int)hq.x, A0, false); \
        A0 = __builtin_amdgcn_sdot4((int)w0.y, (int)hq.y, A0, false); \
        A0 = __builtin_amdgcn_sdot4((int)w0.z, (int)hq.z, A0, false); \
        A0 = __builtin_amdgcn_sdot4((int)w0.w, (int)hq.w, A0, false); \
        A1 = __builtin_amdgcn_sdot4((int)w1.x, (int)hq.x, A1, false); \
        A1 = __builtin_amdgcn_sdot4((int)w1.y, (int)hq.y, A1, false); \
        A1 = __builtin_amdgcn_sdot4((int)w1.z, (int)hq.z, A1, false); \
        A1 = __builtin_amdgcn_sdot4((int)w1.w, (int)hq.w, A1, false); \
        A2 = __builtin_amdgcn_sdot4((int)w2.x, (int)hq.x, A2, false); \
        A2 = __builtin_amdgcn_sdot4((int)w2.y, (int)hq.y, A2, false); \
        A2 = __builtin_amdgcn_sdot4((int)w2.z, (int)hq.z, A2, false); \
        A2 = __builtin_amdgcn_sdot4((int)w2.w, (int)hq.w, A2, false); \
        A3 = __builtin_amdgcn_sdot4((int)w3.x, (int)hq.x, A3, false); \
        A3 = __builtin_amdgcn_sdot4((int)w3.y, (int)hq.y, A3, false); \
        A3 = __builtin_amdgcn_sdot4((int)w3.z, (int)hq.z, A3, false); \
        A3 = __builtin_amdgcn_sdot4((int)w3.w, (int)hq.w, A3, false); \
    }

__global__ void __launch_bounds__(512, 1)
k_pipe(const float* __restrict__ bih1, const float* __restrict__ bhh1,
       float* __restrict__ ws)
{
    __shared__ __align__(16) char hh8[512];
    __shared__ float wred[8];
    __shared__ float hfacs;
    const int blk = blockIdx.x, u = threadIdx.x;
    const int role = blk >> 5, b = blk & 31;
    char* h0i8 = (char*)(ws + OFF_H08);
    unsigned short* gx = (unsigned short*)(ws + OFF_GX);
    unsigned short* catb = (unsigned short*)(ws + OFF_CATB);
    int* flag0 = (int*)(ws + OFF_FLG);         // [32] stride 32
    int* flag1 = flag0 + 1024;

    if (role == 0){
        // ================= lstm0: produce h0[t], publish i8 =================
        const uint4* wp = ((const uint4*)(ws + OFF_W0S)) + u;
        const float* comb = ws + OFF_CMB0;
        const float cb0 = comb[u], cb1 = comb[512+u], cb2 = comb[1024+u], cb3 = comb[1536+u];
        float c = ws[OFF_C0I + b*512 + u];
        float h0v = ws[OFF_H0I + b*512 + u];
        {
            float a = fabsf(h0v);
            #pragma unroll
            for (int msk = 32; msk >= 1; msk >>= 1) a = fmaxf(a, __shfl_xor(a, msk));
            if ((u & 63) == 0) wred[u >> 6] = a;
            __syncthreads();
            if (u == 0){
                float m = wred[0];
                #pragma unroll
                for (int i2 = 1; i2 < 8; ++i2) m = fmaxf(m, wred[i2]);
                hfacs = fmaxf(m, 1.f);
            }
            __syncthreads();
        }
        float hmaxc = hfacs;
        hh8[u] = (char)__float2int_rn(h0v * (127.f/hmaxc));
        __syncthreads();
        for (int t = 0; t < TM1; ++t){
            const unsigned short* grow = gx + ((size_t)(b*127 + t))*2048 + u;
            float gxi = b2f(grow[0]),    gxf = b2f(grow[512]);
            float gxg = b2f(grow[1024]), gxo = b2f(grow[1536]);
            int a0 = 0, a1 = 0, a2 = 0, a3 = 0;
            DOTLOOP(wp, hh8, a0, a1, a2, a3)
            float gi = fmaf((float)a0, cb0*hmaxc, gxi);
            float gf = fmaf((float)a1, cb1*hmaxc, gxf);
            float gg = fmaf((float)a2, cb2*hmaxc, gxg);
            float go = fmaf((float)a3, cb3*hmaxc, gxo);
            float cn = sigm(gf)*c + sigm(gi)*tanh_f(gg);
            float hn = sigm(go)*tanh_f(cn);
            c = cn;
            __syncthreads();
            hmaxc = 1.f;
            hh8[u] = (char)__float2int_rn(hn * 127.f);
            __syncthreads();
            if (u < 64)
                cohs((ull_t*)(h0i8 + ((size_t)(b*127 + t))*512) + u, ((ull_t*)hh8)[u]);
            __syncthreads();            // drain wave0 stores before flag
            if (u == 0) cohsi(flag0 + b*32, t + 1);
        }
    } else if (role == 1){
        // ================= g1x worker: g1[t] = Wih1 @ h0[t] + biases =================
        __shared__ __align__(16) char h8[512];
        const uint4* wp = ((const uint4*)(ws + OFF_WX1)) + u;
        const float* comb = ws + OFF_CMBX;
        const float cb0 = comb[u], cb1 = comb[512+u], cb2 = comb[1024+u], cb3 = comb[1536+u];
        const float gb0 = bih1[u]        + bhh1[u];
        const float gb1 = bih1[512+u]    + bhh1[512+u];
        const float gb2 = bih1[1024+u]   + bhh1[1024+u];
        const float gb3 = bih1[1536+u]   + bhh1[1536+u];
        for (int t = 0; t < TM1; ++t){
            if (u == 0){
                while (cohli(flag0 + b*32) < t + 1) __builtin_amdgcn_s_sleep(2);
            }
            __syncthreads();
            if (u < 64)
                ((ull_t*)h8)[u] = cohl((const ull_t*)(h0i8 + ((size_t)(b*127 + t))*512) + u);
            __syncthreads();
            int a0 = 0, a1 = 0, a2 = 0, a3 = 0;
            DOTLOOP(wp, h8, a0, a1, a2, a3)
            unsigned short* gr = gx + ((size_t)(b*127 + t))*2048;
            cohss(gr + u,      f2b(fmaf((float)a0, cb0, gb0)));
            cohss(gr + 512+u,  f2b(fmaf((float)a1, cb1, gb1)));
            cohss(gr + 1024+u, f2b(fmaf((float)a2, cb2, gb2)));
            cohss(gr + 1536+u, f2b(fmaf((float)a3, cb3, gb3)));
            __syncthreads();            // all waves' gate stores drained
            if (u == 0) cohsi(flag1 + b*32, t + 1);
        }
    } else {
        // ================= lstm1: consume g1[t], own Whh1 recurrence =================
        const uint4* wp = ((const uint4*)(ws + OFF_W1S)) + u;
        const float* comb = ws + OFF_CMB1;
        const float cb0 = comb[u], cb1 = comb[512+u], cb2 = comb[1024+u], cb3 = comb[1536+u];
        float c = ws[OFF_C1I + b*512 + u];
        float h1v = ws[OFF_H1I + b*512 + u];
        {
            float a = fabsf(h1v);
            #pragma unroll
            for (int msk = 32; msk >= 1; msk >>= 1) a = fmaxf(a, __shfl_xor(a, msk));
            if ((u & 63) == 0) wred[u >> 6] = a;
            __syncthreads();
            if (u == 0){
                float m = wred[0];
                #pragma unroll
                for (int i2 = 1; i2 < 8; ++i2) m = fmaxf(m, wred[i2]);
                hfacs = fmaxf(m, 1.f);
            }
            __syncthreads();
        }
        float hmaxc = hfacs;
        hh8[u] = (char)__float2int_rn(h1v * (127.f/hmaxc));
        __syncthreads();
        for (int t = 0; t < TM1; ++t){
            if (u == 0){
                while (cohli(flag1 + b*32) < t + 1) __builtin_amdgcn_s_sleep(2);
            }
            __syncthreads();
            const unsigned short* gr = gx + ((size_t)(b*127 + t))*2048;
            float gxi = b2f(cohls(gr + u));
            float gxf = b2f(cohls(gr + 512+u));
            float gxg = b2f(cohls(gr + 1024+u));
            float gxo = b2f(cohls(gr + 1536+u));
            int a0 = 0, a1 = 0, a2 = 0, a3 = 0;
            DOTLOOP(wp, hh8, a0, a1, a2, a3)
            float gi = fmaf((float)a0, cb0*hmaxc, gxi);
            float gf = fmaf((float)a1, cb1*hmaxc, gxf);
            float gg = fmaf((float)a2, cb2*hmaxc, gxg);
            float go = fmaf((float)a3, cb3*hmaxc, gxo);
            float cn = sigm(gf)*c + sigm(gi)*tanh_f(gg);
            float hn = sigm(go)*tanh_f(cn);
            c = cn;
            __syncthreads();
            hmaxc = 1.f;
            hh8[u] = (char)__float2int_rn(hn * 127.f);
            catb[((size_t)(t*32 + b))*1024 + u] = f2b(hn);
            __syncthreads();
        }
    }
}

// ------------------------------------------------------------------ generic MFMA GEMM
__global__ void __launch_bounds__(256)
k_gemm(const unsigned short* __restrict__ A, int lda,
       const float* __restrict__ B, int ldb,
       const float* __restrict__ bias1, const float* __restrict__ bias2,
       unsigned short* __restrict__ C, int ldc, int nkk)
{
    __shared__ unsigned short As[128*32];
    __shared__ unsigned short Bs[128*32];
    const int tid = threadIdx.x;
    const int mt = blockIdx.x, nt = blockIdx.y;
    const int m0 = mt*128, n0 = nt*128;
    const int lane = tid & 63, wid = tid >> 6;
    const int wr = wid >> 1, wc = wid & 1;
    const int lr = lane & 15, lg = lane >> 4;
    const int ar = tid & 127, ah = tid >> 7;
    const int br = tid >> 1,  bh = tid & 1;
    f32x4 acc[4][4];
    #pragma unroll
    for (int i=0;i<4;i++)
        #pragma unroll
        for (int j=0;j<4;j++) acc[i][j] = (f32x4){0.f,0.f,0.f,0.f};

    for (int kk = 0; kk < nkk; ++kk){
        const int k0 = kk*32;
        uint4 a0 = *(const uint4*)(A + (size_t)(m0+ar)*lda + k0 + ah*16);
        uint4 a1 = *(const uint4*)(A + (size_t)(m0+ar)*lda + k0 + ah*16 + 8);
        const float* bsrc = B + (size_t)(n0+br)*ldb + k0 + bh*16;
        float4 f0 = *(const float4*)(bsrc);
        float4 f1 = *(const float4*)(bsrc+4);
        float4 f2 = *(const float4*)(bsrc+8);
        float4 f3 = *(const float4*)(bsrc+12);
        __syncthreads();
        {
            int swz = (ar>>1)&3;
            *(uint4*)&As[ar*32 + ((2*ah  )^swz)*8] = a0;
            *(uint4*)&As[ar*32 + ((2*ah+1)^swz)*8] = a1;
        }
        {
            uint4 p0, p1;
            p0.x = __builtin_amdgcn_perm(__float_as_uint(f0.y), __float_as_uint(f0.x), 0x07060302u);
            p0.y = __builtin_amdgcn_perm(__float_as_uint(f0.w), __float_as_uint(f0.z), 0x07060302u);
            p0.z = __builtin_amdgcn_perm(__float_as_uint(f1.y), __float_as_uint(f1.x), 0x07060302u);
            p0.w = __builtin_amdgcn_perm(__float_as_uint(f1.w), __float_as_uint(f1.z), 0x07060302u);
            p1.x = __builtin_amdgcn_perm(__float_as_uint(f2.y), __float_as_uint(f2.x), 0x07060302u);
            p1.y = __builtin_amdgcn_perm(__float_as_uint(f2.w), __float_as_uint(f2.z), 0x07060302u);
            p1.z = __builtin_amdgcn_perm(__float_as_uint(f3.y), __float_as_uint(f3.x), 0x07060302u);
            p1.w = __builtin_amdgcn_perm(__float_as_uint(f3.w), __float_as_uint(f3.z), 0x07060302u);
            int swz = (br>>1)&3;
            *(uint4*)&Bs[br*32 + ((2*bh  )^swz)*8] = p0;
            *(uint4*)&Bs[br*32 + ((2*bh+1)^swz)*8] = p1;
        }
        __syncthreads();
        short8 av[4], bv[4];
        #pragma unroll
        for (int mi=0; mi<4; ++mi){
            int r = wr*64 + mi*16 + lr;
            av[mi] = *(const short8*)&As[r*32 + ((lg ^ ((r>>1)&3))*8)];
        }
        #pragma unroll
        for (int ni=0; ni<4; ++ni){
            int r = wc*64 + ni*16 + lr;
            bv[ni] = *(const short8*)&Bs[r*32 + ((lg ^ ((r>>1)&3))*8)];
        }
        #pragma unroll
        for (int mi=0; mi<4; ++mi)
            #pragma unroll
            for (int ni=0; ni<4; ++ni)
                acc[mi][ni] = __builtin_amdgcn_mfma_f32_16x16x32_bf16(av[mi], bv[ni], acc[mi][ni], 0, 0, 0);
    }
    int coln[4]; float bsv[4];
    #pragma unroll
    for (int ni=0; ni<4; ++ni){
        coln[ni] = n0 + wc*64 + ni*16 + lr;
        float bv2 = 0.f;
        if (bias1) bv2 += bias1[coln[ni]];
        if (bias2) bv2 += bias2[coln[ni]];
        bsv[ni] = bv2;
    }
    #pragma unroll
    for (int mi=0; mi<4; ++mi)
        #pragma unroll
        for (int ni=0; ni<4; ++ni)
            #pragma unroll
            for (int reg=0; reg<4; ++reg){
                int row = m0 + wr*64 + mi*16 + lg*4 + reg;
                C[(size_t)row*ldc + coln[ni]] = f2b(acc[mi][ni][reg] + bsv[ni]);
            }
}

// ------------------------------------------------------------------ attention per (t,b)
__global__ void __launch_bounds__(256)
k_att(const float* __restrict__ enc, const float* __restrict__ v, float* __restrict__ ws){
    __shared__ float hqs[512], vv[512], att[128], rbuf[2];
    const int m = blockIdx.x, tid = threadIdx.x;
    const int b = m & 31;
    const unsigned short* hq = (const unsigned short*)(ws + OFF_HQ) + (size_t)m*512;
    const unsigned short* encwb = (const unsigned short*)(ws + OFF_ENCW);
    unsigned short* catb = (unsigned short*)(ws + OFF_CATB);
    hqs[tid] = b2f(hq[tid]); hqs[tid+256] = b2f(hq[tid+256]);
    vv[tid] = v[tid];        vv[tid+256] = v[tid+256];
    __syncthreads();
    {
        int s = tid >> 1, q = tid & 1;
        const unsigned short* eb = encwb + ((size_t)(b*SS + s))*512 + q*256;
        const float* hp = hqs + q*256;
        const float* vp = vv + q*256;
        float p0 = 0.f, p1 = 0.f;
        #pragma unroll 2
        for (int k = 0; k < 256; k += 2){
            p0 += tanh_f(hp[k]   + b2f(eb[k]))   * vp[k];
            p1 += tanh_f(hp[k+1] + b2f(eb[k+1])) * vp[k+1];
        }
        float p = p0 + p1;
        p += __shfl_xor(p, 1);
        if (q == 0) att[s] = p;
    }
    __syncthreads();
    float e0 = 0.f, e1 = 0.f;
    if (tid < 64){
        float m2 = fmaxf(att[tid], att[tid+64]);
        #pragma unroll
        for (int msk = 32; msk >= 1; msk >>= 1) m2 = fmaxf(m2, __shfl_xor(m2, msk));
        if (tid == 0) rbuf[0] = m2;
    }
    __syncthreads();
    float M = rbuf[0];
    if (tid < 64){
        e0 = __expf(att[tid] - M);
        e1 = __expf(att[tid+64] - M);
        float sum = e0 + e1;
        #pragma unroll
        for (int msk = 32; msk >= 1; msk >>= 1) sum += __shfl_xor(sum, msk);
        if (tid == 0) rbuf[1] = sum;
    }
    __syncthreads();
    if (tid < 64){
        float inv = 1.f / rbuf[1];
        att[tid] = e0*inv; att[tid+64] = e1*inv;
    }
    __syncthreads();
    {
        const float* eb2 = enc + (size_t)(b*SS)*512;
        float w0 = 0.f, w1 = 0.f;
        #pragma unroll 4
        for (int s = 0; s < 128; ++s){
            float a = att[s];
            w0 += a * eb2[s*512 + tid];
            w1 += a * eb2[s*512 + tid + 256];
        }
        catb[((size_t)m)*1024 + 512 + tid] = f2b(w0);
        catb[((size_t)m)*1024 + 768 + tid] = f2b(w1);
    }
}

// ------------------------------------------------------------------ fc MFMA GEMM + LSE partials
__global__ void __launch_bounds__(256)
k_fc(const float* __restrict__ fcW, const float* __restrict__ fcb, float* __restrict__ ws){
    __shared__ unsigned short As[128*32];
    __shared__ unsigned short Bs[128*32];
    __shared__ float eM[128], eS[128];
    const int tid = threadIdx.x;
    const int bid = blockIdx.x;
    const int g = (bid & 7)*1000 + (bid >> 3);
    const int nt = g / 32, mt = g % 32;
    const int m0 = mt*128, n0 = nt*128;
    const unsigned short* catb = (const unsigned short*)(ws + OFF_CATB);
    const int lane = tid & 63, wid = tid >> 6;
    const int wr = wid >> 1, wc = wid & 1;
    const int lr = lane & 15, lg = lane >> 4;
    const int ar = tid & 127, ah = tid >> 7;
    const int br = tid >> 1,  bh = tid & 1;
    f32x4 acc[4][4];
    #pragma unroll
    for (int i=0;i<4;i++)
        #pragma unroll
        for (int j=0;j<4;j++) acc[i][j] = (f32x4){0.f,0.f,0.f,0.f};

    for (int kk = 0; kk < 32; ++kk){
        const int k0 = kk*32;
        uint4 a0 = *(const uint4*)(catb + (size_t)(m0+ar)*1024 + k0 + ah*16);
        uint4 a1 = *(const uint4*)(catb + (size_t)(m0+ar)*1024 + k0 + ah*16 + 8);
        const float* bsrc = fcW + (size_t)(n0+br)*1024 + k0 + bh*16;
        float4 f0 = *(const float4*)(bsrc);
        float4 f1 = *(const float4*)(bsrc+4);
        float4 f2 = *(const float4*)(bsrc+8);
        float4 f3 = *(const float4*)(bsrc+12);
        __syncthreads();
        {
            int swz = (ar>>1)&3;
            *(uint4*)&As[ar*32 + ((2*ah  )^swz)*8] = a0;
            *(uint4*)&As[ar*32 + ((2*ah+1)^swz)*8] = a1;
        }
        {
            uint4 p0, p1;
            p0.x = __builtin_amdgcn_perm(__float_as_uint(f0.y), __float_as_uint(f0.x), 0x07060302u);
            p0.y = __builtin_amdgcn_perm(__float_as_uint(f0.w), __float_as_uint(f0.z), 0x07060302u);
            p0.z = __builtin_amdgcn_perm(__float_as_uint(f1.y), __float_as_uint(f1.x), 0x07060302u);
            p0.w = __builtin_amdgcn_perm(__float_as_uint(f1.w), __float_as_uint(f1.z), 0x07060302u);
            p1.x = __builtin_amdgcn_perm(__float_as_uint(f2.y), __float_as_uint(f2.x), 0x07060302u);
            p1.y = __builtin_amdgcn_perm(__float_as_uint(f2.w), __float_as_uint(f2.z), 0x07060302u);
            p1.z = __builtin_amdgcn_perm(__float_as_uint(f3.y), __float_as_uint(f3.x), 0x07060302u);
            p1.w = __builtin_amdgcn_perm(__float_as_uint(f3.w), __float_as_uint(f3.z), 0x07060302u);
            int swz = (br>>1)&3;
            *(uint4*)&Bs[br*32 + ((2*bh  )^swz)*8] = p0;
            *(uint4*)&Bs[br*32 + ((2*bh+1)^swz)*8] = p1;
        }
        __syncthreads();
        short8 av[4], bv[4];
        #pragma unroll
        for (int mi=0; mi<4; ++mi){
            int r = wr*64 + mi*16 + lr;
            av[mi] = *(const short8*)&As[r*32 + ((lg ^ ((r>>1)&3))*8)];
        }
        #pragma unroll
        for (int ni=0; ni<4; ++ni){
            int r = wc*64 + ni*16 + lr;
            bv[ni] = *(const short8*)&Bs[r*32 + ((lg ^ ((r>>1)&3))*8)];
        }
        #pragma unroll
        for (int mi=0; mi<4; ++mi)
            #pragma unroll
            for (int ni=0; ni<4; ++ni)
                acc[mi][ni] = __builtin_amdgcn_mfma_f32_16x16x32_bf16(av[mi], bv[ni], acc[mi][ni], 0, 0, 0);
    }
    float bias[4];
    #pragma unroll
    for (int ni=0; ni<4; ++ni) bias[ni] = fcb[n0 + wc*64 + ni*16 + lr];
    float mxA[4][4], smA[4][4];
    #pragma unroll
    for (int mi=0; mi<4; ++mi){
        #pragma unroll
        for (int reg=0; reg<4; ++reg){
            float mx = -3.4e38f;
            #pragma unroll
            for (int ni=0; ni<4; ++ni) mx = fmaxf(mx, acc[mi][ni][reg] + bias[ni]);
            #pragma unroll
            for (int msk=8; msk>=1; msk>>=1) mx = fmaxf(mx, __shfl_xor(mx, msk));
            float sm = 0.f;
            #pragma unroll
            for (int ni=0; ni<4; ++ni) sm += __expf(acc[mi][ni][reg] + bias[ni] - mx);
            #pragma unroll
            for (int msk=8; msk>=1; msk>>=1) sm += __shfl_xor(sm, msk);
            mxA[mi][reg] = mx; smA[mi][reg] = sm;
            if (wc == 0 && lr == 0){
                int rl = wr*64 + mi*16 + lg*4 + reg;
                eM[rl] = mx; eS[rl] = sm;
            }
        }
    }
    __syncthreads();
    if (wc == 1 && lr == 0){
        float2* part = (float2*)(ws + OFF_PART);
        #pragma unroll
        for (int mi=0; mi<4; ++mi){
            #pragma unroll
            for (int reg=0; reg<4; ++reg){
                int rl = wr*64 + mi*16 + lg*4 + reg;
                float m0v = eM[rl], s0 = eS[rl];
                float m1v = mxA[mi][reg], s1 = smA[mi][reg];
                float M = fmaxf(m0v, m1v);
                float S = s0*__expf(m0v - M) + s1*__expf(m1v - M);
                part[(size_t)(m0 + rl)*NT128 + nt] = make_float2(M, S);
            }
        }
    }
}

// ------------------------------------------- per-row LSE combine + target logit
__global__ void k_row(const int* __restrict__ X, const float* __restrict__ fcW,
                      const float* __restrict__ fcb, float* __restrict__ ws){
    __shared__ float LM[256], LS[256];
    int m = blockIdx.x, tid = threadIdx.x;
    const float2* p = (const float2*)(ws + OFF_PART);
    float M = -3.4e38f, Ssum = 0.f;
    if (tid < NT128){
        float2 q = p[(size_t)m*NT128 + tid];
        M = q.x; Ssum = q.y;
    }
    LM[tid] = M; LS[tid] = Ssum;
    __syncthreads();
    for (int off = 128; off >= 1; off >>= 1){
        if (tid < off){
            float m1 = LM[tid], s1 = LS[tid];
            float m2 = LM[tid+off], s2 = LS[tid+off];
            float mm = fmaxf(m1, m2);
            LM[tid] = mm;
            LS[tid] = s1*__expf(m1-mm) + s2*__expf(m2-mm);
        }
        __syncthreads();
    }
    float lse = LM[0] + __logf(LS[0]);
    __syncthreads();
    int t = m >> 5, b = m & 31;
    int y = X[b*TT + t + 1];
    const unsigned short* cr = (const unsigned short*)(ws + OFF_CATB) + (size_t)m*1024;
    const float* wr = fcW + (size_t)y*1024;
    float a = 0.f;
    #pragma unroll
    for (int k = 0; k < 4; ++k) a += b2f(cr[tid*4+k]) * wr[tid*4+k];
    LM[tid] = a;
    __syncthreads();
    for (int off = 128; off >= 1; off >>= 1){
        if (tid < off) LM[tid] += LM[tid+off];
        __syncthreads();
    }
    if (tid == 0){
        float tl = LM[0] + fcb[y];
        float nll = lse - tl;
        int valid = (y != 0);
        ws[OFF_NLL + m] = valid ? nll : 0.f;
        ws[OFF_CNT + m] = valid ? 1.f : 0.f;
    }
}

// ------------------------------------------------------------------ finalize
__global__ void k_fin(const float* __restrict__ ws, float* __restrict__ out){
    __shared__ float red[256];
    int tid = threadIdx.x;
    float lt = 0.f;
    if (tid < TM1){
        float s = 0.f, c = 0.f;
        for (int b=0;b<NB;b++){
            s += ws[OFF_NLL + tid*NB + b];
            c += ws[OFF_CNT + tid*NB + b];
        }
        lt = s / fmaxf(c, 1.f);
    }
    red[tid] = lt;
    __syncthreads();
    for (int off=128; off>=1; off>>=1){
        if (tid < off) red[tid] += red[tid+off];
        __syncthreads();
    }
    if (tid == 0) out[0] = red[0] / (float)TM1;
}

// -------------------------------------------------------------------- launch
extern "C" void kernel_launch(void* const* d_in, const int* in_sizes, int n_in,
                              void* d_out, int out_size, void* d_ws, size_t ws_size,
                              hipStream_t stream) {
    const int*   X     = (const int*)  d_in[0];
    const float* enc   = (const float*)d_in[1];
    const float* hid   = (const float*)d_in[2];
    const float* cel   = (const float*)d_in[3];
    const float* emb   = (const float*)d_in[4];
    const float* Wih0  = (const float*)d_in[5];
    const float* Whh0  = (const float*)d_in[6];
    const float* bih0  = (const float*)d_in[7];
    const float* bhh0  = (const float*)d_in[8];
    const float* Wih1  = (const float*)d_in[9];
    const float* Whh1  = (const float*)d_in[10];
    const float* bih1  = (const float*)d_in[11];
    const float* bhh1  = (const float*)d_in[12];
    const float* attnW = (const float*)d_in[13];
    const float* attnb = (const float*)d_in[14];
    const float* v     = (const float*)d_in[15];
    const float* fcW   = (const float*)d_in[16];
    const float* fcb   = (const float*)d_in[17];
    float* ws  = (float*)d_ws;
    float* out = (float*)d_out;

    unsigned short* catb = (unsigned short*)(ws + OFF_CATB);
    unsigned short* hq   = (unsigned short*)(ws + OFF_HQ);
    unsigned short* encb = (unsigned short*)(ws + OFF_ENCB);
    unsigned short* embb = (unsigned short*)(ws + OFF_EMBB);
    unsigned short* encw = (unsigned short*)(ws + OFF_ENCW);
    unsigned short* g0x  = (unsigned short*)(ws + OFF_GX);

    k_init<<<320, 256, 0, stream>>>(hid, cel, ws);
    k_qpack<<<6144, 256, 0, stream>>>(Whh0, Whh1, Wih1, ws);
    k_cvt<<<3065, 256, 0, stream>>>(X, emb, enc, ws);
    // encW = enc_bf16 @ attnW[:,512:]^T + attnb
    k_gemm<<<dim3(32,4), 256, 0, stream>>>(encb, 512, attnW + 512, 1024,
                                           attnb, (const float*)nullptr,
                                           encw, 512, 16);
    // g0x = emb_bf16 @ Wih0^T + biases
    k_gemm<<<dim3(32,16), 256, 0, stream>>>(embb, 256, Wih0, 256, bih0, bhh0,
                                            g0x, 2048, 8);
    // 3-stage pipelined scan (lstm0 || g1x || lstm1)
    {
        void* args[] = {(void*)&bih1, (void*)&bhh1, (void*)&ws};
        (void)hipLaunchCooperativeKernel((const void*)k_pipe, dim3(96), dim3(512),
                                         args, 0, stream);
    }
    // hq = h1 @ attnW_q^T
    k_gemm<<<dim3(32,4), 256, 0, stream>>>(catb, 1024, attnW, 1024,
                                           (const float*)nullptr, (const float*)nullptr,
                                           hq, 512, 16);
    k_att<<<NROWS, 256, 0, stream>>>(enc, v, ws);
    k_fc<<<8000, 256, 0, stream>>>(fcW, fcb, ws);
    k_row<<<NROWS, 256, 0, stream>>>(X, fcW, fcb, ws);
    k_fin<<<1, 256, 0, stream>>>(ws, out);
}